// Round 4
// baseline (633.662 us; speedup 1.0000x reference)
//
#include <hip/hip_runtime.h>
#include <hip/hip_bf16.h>
#include <math.h>

// ---------------------------------------------------------------------------
// Transformer block, bf16-MFMA path (MI355X / gfx950).
// Pipeline: cast -> QKV GEMMs -> V transpose -> flash attention -> WO GEMM
//           -> add+LN1 -> FF1(+GELU, 8-phase 256^2) -> FF2 -> add+LN2 -> out
// Round 4: FF1 moved to a 256x256 8-phase double-buffered schedule
// (T2 swizzle + T3/T4 counted vmcnt + T5 setprio + T1 XCD swizzle).
// Everything else identical to round 3 (attn: 139us, conflicts=0).
// ---------------------------------------------------------------------------

typedef __attribute__((ext_vector_type(8))) short short8;   // 8 x bf16 (4 VGPR)
typedef __attribute__((ext_vector_type(4))) float f32x4;    // MFMA accumulator

__device__ __forceinline__ unsigned short f2bf(float f) {
  unsigned int u = __builtin_bit_cast(unsigned int, f);
  u = (u + 0x7fffu + ((u >> 16) & 1u)) >> 16;   // RNE
  return (unsigned short)u;
}
__device__ __forceinline__ float bf2f(unsigned short h) {
  unsigned int u = ((unsigned int)h) << 16;
  return __builtin_bit_cast(float, u);
}
__device__ __forceinline__ f32x4 mfma16(short8 a, short8 b, f32x4 c) {
  // D[(lane>>4)*4+j][lane&15] += sum_k A[lane&15][8*(lane>>4)+i] * B[8*(lane>>4)+i][lane&15]
  return __builtin_amdgcn_mfma_f32_16x16x32_bf16(a, b, c, 0, 0, 0);
}
__device__ __forceinline__ void gload16(const void* g, void* l) {
  // async global->LDS, 16B per lane; LDS dest must be wave-uniform base + lane*16
  __builtin_amdgcn_global_load_lds((const __attribute__((address_space(1))) void*)g,
                                   (__attribute__((address_space(3))) void*)l, 16, 0, 0);
}

// ------------------------------- cast --------------------------------------
__global__ void cast_f32_bf16(const float* __restrict__ in,
                              unsigned short* __restrict__ out, int n4) {
  for (int i = blockIdx.x * blockDim.x + threadIdx.x; i < n4;
       i += gridDim.x * blockDim.x) {
    float4 v = ((const float4*)in)[i];
    ushort4 o;
    o.x = f2bf(v.x); o.y = f2bf(v.y); o.z = f2bf(v.z); o.w = f2bf(v.w);
    ((ushort4*)out)[i] = o;
  }
}

// ------------------------------- GEMM (NT), 128^2 2-phase ------------------
// C[M,N] = A[M,K] * W[N,K]^T + bias. EPI: 0=none, 1=exact GELU, 2=scale 1/8.
template<int EPI>
__global__ void gemm_bt(const unsigned short* __restrict__ A,
                        const unsigned short* __restrict__ W,
                        const float* __restrict__ bias,
                        unsigned short* __restrict__ C,
                        int M, int N, int K) {
  __shared__ unsigned short As[128 * 64];   // [row][64k] linear, 128B rows
  __shared__ unsigned short Bs[128 * 64];
  const int t = threadIdx.x;
  const int lane = t & 63, w = t >> 6;
  const int l15 = lane & 15, l4 = lane >> 4;
  const int m0 = blockIdx.y * 128, n0 = blockIdx.x * 128;
  const int wr = (w >> 1) * 64, wc = (w & 1) * 64;
  f32x4 acc[4][4] = {};
  const int srow = t >> 3;          // 0..31 : row within a 32-row round
  const int scol = (t & 7) * 16;    // byte offset within 128B row

  for (int k0 = 0; k0 < K; k0 += 64) {
    __syncthreads();                // all waves done reading previous tile
#pragma unroll
    for (int r = 0; r < 4; ++r) {
      int row = r * 32 + srow;
      gload16((const char*)(A + (size_t)(m0 + row) * K + k0) + scol,
              (char*)As + row * 128 + scol);
    }
#pragma unroll
    for (int r = 0; r < 4; ++r) {
      int row = r * 32 + srow;
      gload16((const char*)(W + (size_t)(n0 + row) * K + k0) + scol,
              (char*)Bs + row * 128 + scol);
    }
    __syncthreads();                // staged (syncthreads drains vmcnt)
#pragma unroll
    for (int ks = 0; ks < 2; ++ks) {
      short8 af[4], bfr[4];
#pragma unroll
      for (int m = 0; m < 4; ++m)
        af[m] = *(const short8*)((const char*)As + (wr + m * 16 + l15) * 128 +
                                 ks * 64 + l4 * 16);
#pragma unroll
      for (int n = 0; n < 4; ++n)
        bfr[n] = *(const short8*)((const char*)Bs + (wc + n * 16 + l15) * 128 +
                                  ks * 64 + l4 * 16);
#pragma unroll
      for (int m = 0; m < 4; ++m)
#pragma unroll
        for (int n = 0; n < 4; ++n)
          acc[m][n] = mfma16(af[m], bfr[n], acc[m][n]);
    }
  }
#pragma unroll
  for (int n = 0; n < 4; ++n) {
    int col = n0 + wc + n * 16 + l15;
    float bcol = bias[col];
#pragma unroll
    for (int m = 0; m < 4; ++m) {
      int row = m0 + wr + m * 16 + l4 * 4;
#pragma unroll
      for (int j = 0; j < 4; ++j) {
        float v = acc[m][n][j] + bcol;
        if (EPI == 1) v = 0.5f * v * (1.0f + erff(v * 0.70710678118654752f));
        if (EPI == 2) v *= 0.125f;
        C[(size_t)(row + j) * N + col] = f2bf(v);
      }
    }
  }
}

// ------------------- GEMM (NT), 256^2 8-phase pipelined --------------------
// 512 thr (8 waves, 2M x 4N), BK=64, LDS 128KiB double-buffered, XOR-swizzled
// (chunk ^= row&7 at 16B granularity; pre-swizzled global source).
// Per K-tile: 4 phases (mh-major). Staging units (16KB, 2 gloads/thread):
//   A-mh0 = A rows {0-63,128-191}, A-mh1 = rows {64-127,192-255},
//   B-lo = W rows 0-127, B-hi = rows 128-255.
// Region liveness: A-mh0 & B dead after ph1's end-barrier; A-mh1 after ph3.
// Stage schedule (tile T): ph0->Bhi(T+1), ph1->Amh1(T+1),
//                          ph2->Amh0(T+2), ph3->Blo(T+2).
// Wait schedule: vmcnt(8) end of ph1 (guards Amh1(T) for ph2),
//                vmcnt(6) end of ph3 (guards Amh0/Blo/Bhi(T+1) for next ph0).
// Last 3 tiles: vmcnt(0) (safe tail). Queue proof in round-4 notes.
template<int EPI>
__global__ __launch_bounds__(512, 2)
void gemm_bt8(const unsigned short* __restrict__ A,
              const unsigned short* __restrict__ W,
              const float* __restrict__ bias,
              unsigned short* __restrict__ C,
              int M, int N, int K, int nbx) {
  __shared__ unsigned short lds[2][2][256 * 64];  // [buf][0=A,1=B][row*64]
  const int t = threadIdx.x;
  const int lane = t & 63, wid = t >> 6;
  const int wm = wid >> 2, wn = wid & 3;
  const int l15 = lane & 15, l4 = lane >> 4;
  const int rchk = l15 & 7;
  // T1: XCD-bijective block swizzle (grid % 8 == 0 by construction)
  const int nwg = gridDim.x, cpx = nwg >> 3;
  const int orig = blockIdx.x;
  const int bid = (orig & 7) * cpx + (orig >> 3);
  const int m0 = (bid / nbx) * 256, n0 = (bid % nbx) * 256;
  const int NT = K >> 6;

  auto stageA = [&](int buf, int half, int Tt) {
#pragma unroll
    for (int i = 0; i < 2; ++i) {
      int q = t + 512 * i;
      int rl = q >> 3, c = q & 7;
      int row = half * 64 + (rl & 63) + (rl >> 6) * 128;
      int gc = (c ^ (row & 7)) * 16;
      gload16((const char*)(A + (size_t)(m0 + row) * K + Tt * 64) + gc,
              (char*)&lds[buf][0][0] + row * 128 + c * 16);
    }
  };
  auto stageB = [&](int buf, int half, int Tt) {
#pragma unroll
    for (int i = 0; i < 2; ++i) {
      int q = t + 512 * i;
      int rl = q >> 3, c = q & 7;
      int row = half * 128 + rl;
      int gc = (c ^ (row & 7)) * 16;
      gload16((const char*)(W + (size_t)(n0 + row) * K + Tt * 64) + gc,
              (char*)&lds[buf][1][0] + row * 128 + c * 16);
    }
  };

  f32x4 acc[8][4] = {};
  short8 bfr[2][4];

  // prologue: tile0 complete + Amh0/Blo of tile1; wait tile0 landed.
  stageA(0, 0, 0); stageB(0, 0, 0); stageB(0, 1, 0); stageA(0, 1, 0);
  if (NT > 1) { stageA(1, 0, 1); stageB(1, 0, 1); }
  asm volatile("s_waitcnt vmcnt(4)" ::: "memory");
  __builtin_amdgcn_s_barrier();

  for (int T = 0; T < NT; ++T) {
    const int buf = T & 1;
    const char* Ab = (const char*)&lds[buf][0][0];
    const char* Bb = (const char*)&lds[buf][1][0];
    const bool sK1 = (T + 1) < NT, sK2 = (T + 2) < NT;
    const bool tail = (T >= NT - 3);
    short8 af[4];

    // ---- phase 0: (mh0,ks0) ---- stage Bhi(T+1); read B(ks0)x4 + A x4
    if (sK1) stageB(buf ^ 1, 1, T + 1);
#pragma unroll
    for (int n = 0; n < 4; ++n)
      bfr[0][n] = *(const short8*)(Bb + (wn * 64 + n * 16 + l15) * 128 +
                                   ((l4 ^ rchk) * 16));
#pragma unroll
    for (int m = 0; m < 4; ++m)
      af[m] = *(const short8*)(Ab + (wm * 128 + m * 16 + l15) * 128 +
                               ((l4 ^ rchk) * 16));
    __builtin_amdgcn_s_barrier();
    asm volatile("s_waitcnt lgkmcnt(0)" ::: "memory");
    __builtin_amdgcn_sched_barrier(0);
    __builtin_amdgcn_s_setprio(1);
#pragma unroll
    for (int m = 0; m < 4; ++m)
#pragma unroll
      for (int n = 0; n < 4; ++n)
        acc[m][n] = mfma16(af[m], bfr[0][n], acc[m][n]);
    __builtin_amdgcn_s_setprio(0);
    __builtin_amdgcn_s_barrier();

    // ---- phase 1: (mh0,ks1) ---- stage Amh1(T+1); read B(ks1)x4 + A x4
    if (sK1) stageA(buf ^ 1, 1, T + 1);
#pragma unroll
    for (int n = 0; n < 4; ++n)
      bfr[1][n] = *(const short8*)(Bb + (wn * 64 + n * 16 + l15) * 128 +
                                   (((4 + l4) ^ rchk) * 16));
#pragma unroll
    for (int m = 0; m < 4; ++m)
      af[m] = *(const short8*)(Ab + (wm * 128 + m * 16 + l15) * 128 +
                               (((4 + l4) ^ rchk) * 16));
    __builtin_amdgcn_s_barrier();
    asm volatile("s_waitcnt lgkmcnt(0)" ::: "memory");
    __builtin_amdgcn_sched_barrier(0);
    __builtin_amdgcn_s_setprio(1);
#pragma unroll
    for (int m = 0; m < 4; ++m)
#pragma unroll
      for (int n = 0; n < 4; ++n)
        acc[m][n] = mfma16(af[m], bfr[1][n], acc[m][n]);
    __builtin_amdgcn_s_setprio(0);
    if (tail) asm volatile("s_waitcnt vmcnt(0)" ::: "memory");
    else      asm volatile("s_waitcnt vmcnt(8)" ::: "memory");
    __builtin_amdgcn_s_barrier();

    // ---- phase 2: (mh1,ks0) ---- stage Amh0(T+2); read A x4 (reuse B ks0)
    if (sK2) stageA(buf, 0, T + 2);
#pragma unroll
    for (int m = 0; m < 4; ++m)
      af[m] = *(const short8*)(Ab + (wm * 128 + 64 + m * 16 + l15) * 128 +
                               ((l4 ^ rchk) * 16));
    __builtin_amdgcn_s_barrier();
    asm volatile("s_waitcnt lgkmcnt(0)" ::: "memory");
    __builtin_amdgcn_sched_barrier(0);
    __builtin_amdgcn_s_setprio(1);
#pragma unroll
    for (int m = 0; m < 4; ++m)
#pragma unroll
      for (int n = 0; n < 4; ++n)
        acc[4 + m][n] = mfma16(af[m], bfr[0][n], acc[4 + m][n]);
    __builtin_amdgcn_s_setprio(0);
    __builtin_amdgcn_s_barrier();

    // ---- phase 3: (mh1,ks1) ---- stage Blo(T+2); read A x4 (reuse B ks1)
    if (sK2) stageB(buf, 0, T + 2);
#pragma unroll
    for (int m = 0; m < 4; ++m)
      af[m] = *(const short8*)(Ab + (wm * 128 + 64 + m * 16 + l15) * 128 +
                               (((4 + l4) ^ rchk) * 16));
    __builtin_amdgcn_s_barrier();
    asm volatile("s_waitcnt lgkmcnt(0)" ::: "memory");
    __builtin_amdgcn_sched_barrier(0);
    __builtin_amdgcn_s_setprio(1);
#pragma unroll
    for (int m = 0; m < 4; ++m)
#pragma unroll
      for (int n = 0; n < 4; ++n)
        acc[4 + m][n] = mfma16(af[m], bfr[1][n], acc[4 + m][n]);
    __builtin_amdgcn_s_setprio(0);
    if (tail) asm volatile("s_waitcnt vmcnt(0)" ::: "memory");
    else      asm volatile("s_waitcnt vmcnt(6)" ::: "memory");
    __builtin_amdgcn_s_barrier();
  }

  // epilogue: bias (+GELU), bf16 store
#pragma unroll
  for (int n = 0; n < 4; ++n) {
    int col = n0 + wn * 64 + n * 16 + l15;
    float bcol = bias[col];
#pragma unroll
    for (int mh = 0; mh < 2; ++mh)
#pragma unroll
      for (int m = 0; m < 4; ++m) {
        int row = m0 + wm * 128 + mh * 64 + m * 16 + l4 * 4;
#pragma unroll
        for (int j = 0; j < 4; ++j) {
          float v = acc[mh * 4 + m][n][j] + bcol;
          if (EPI == 1) v = 0.5f * v * (1.0f + erff(v * 0.70710678118654752f));
          if (EPI == 2) v *= 0.125f;
          C[(size_t)(row + j) * N + col] = f2bf(v);
        }
      }
  }
}

// --------------------- V transpose: [b,s,h,d] -> [b,h,d,s] ------------------
__global__ void transpose_v(const unsigned short* __restrict__ v,
                            unsigned short* __restrict__ vt) {
  __shared__ unsigned short tile[64][66];   // pad 66 to break bank conflicts
  const int bh = blockIdx.y;                // b*16+h
  const int b = bh >> 4, h = bh & 15;
  const int s0 = blockIdx.x * 64;
  const int t = threadIdx.x;
  const int sr = t >> 2;          // 0..63 source s-row
  const int dc = (t & 3) * 16;    // d chunk
  const unsigned short* src =
      v + ((size_t)(b * 2048 + s0 + sr) * 1024 + h * 64 + dc);
  short8 a0 = *(const short8*)src;
  short8 a1 = *(const short8*)(src + 8);
#pragma unroll
  for (int i = 0; i < 8; ++i) tile[sr][dc + i] = (unsigned short)a0[i];
#pragma unroll
  for (int i = 0; i < 8; ++i) tile[sr][dc + 8 + i] = (unsigned short)a1[i];
  __syncthreads();
  const int dr = t >> 2;          // 0..63 dest d-row
  const int sc = (t & 3) * 16;    // s chunk
  short8 o0, o1;
#pragma unroll
  for (int i = 0; i < 8; ++i) o0[i] = (short)tile[sc + i][dr];
#pragma unroll
  for (int i = 0; i < 8; ++i) o1[i] = (short)tile[sc + 8 + i][dr];
  unsigned short* dst = vt + ((size_t)(bh * 64 + dr) * 2048 + s0 + sc);
  *(short8*)dst = o0;
  *(short8*)(dst + 8) = o1;
}

// --------------------------- flash attention -------------------------------
// (unchanged from round 3: 139us, MfmaUtil 21%, bank conflicts 0)
__global__ void attn_fwd(const unsigned short* __restrict__ Q,
                         const unsigned short* __restrict__ K,
                         const unsigned short* __restrict__ Vt,
                         unsigned short* __restrict__ O) {
  __shared__ unsigned short Ks[64 * 64];    // [kk][d]  rows 128B, swizzled
  __shared__ unsigned short Vs[64 * 64];    // [d][kk]  rows 128B, swizzled
  __shared__ unsigned short Ps[4][32 * 64]; // per-wave [q][kk], swizzled
  const int bh = blockIdx.y;
  const int b = bh >> 4, h = bh & 15;
  const int q0 = blockIdx.x * 128;
  const int t = threadIdx.x;
  const int lane = t & 63, w = t >> 6;
  const int l15 = lane & 15, l4 = lane >> 4;
  const int swl = (l15 & 7) << 4;           // read-side XOR for row=...+l15

  short8 qf[2][2];
#pragma unroll
  for (int m = 0; m < 2; ++m) {
    const unsigned short* qp =
        Q + ((size_t)(b * 2048 + q0 + w * 32 + m * 16 + l15) * 1024 +
             h * 64 + l4 * 8);
    qf[m][0] = *(const short8*)qp;
    qf[m][1] = *(const short8*)(qp + 32);
  }

  f32x4 o_acc[2][4] = {};
  float l_part[2][4] = {};

  const int srow = t >> 3;      // 0..31: staging row within 32-row round
  const int schk = t & 7;       // staging 16B chunk index
  unsigned short* pw = &Ps[w][0];

#pragma unroll 1
  for (int kt = 0; kt < 32; ++kt) {
    __syncthreads();
#pragma unroll
    for (int r = 0; r < 2; ++r) {
      int row = r * 32 + srow;
      int gofs = (schk ^ (row & 7)) << 4;   // pre-swizzled global source
      gload16((const char*)(K + (size_t)(b * 2048 + kt * 64 + row) * 1024 +
                            h * 64) + gofs,
              (char*)Ks + row * 128 + schk * 16);
      gload16((const char*)(Vt + (size_t)(bh * 64 + row) * 2048 + kt * 64) + gofs,
              (char*)Vs + row * 128 + schk * 16);
    }
    __syncthreads();

    f32x4 s_acc[2][4] = {};
#pragma unroll
    for (int c = 0; c < 4; ++c) {
      const char* krow = (const char*)Ks + (c * 16 + l15) * 128;
      short8 kf0 = *(const short8*)(krow + ((l4 * 16) ^ swl));
      short8 kf1 = *(const short8*)(krow + ((64 + l4 * 16) ^ swl));
#pragma unroll
      for (int m = 0; m < 2; ++m) {
        s_acc[m][c] = mfma16(qf[m][0], kf0, s_acc[m][c]);
        s_acc[m][c] = mfma16(qf[m][1], kf1, s_acc[m][c]);
      }
    }
#pragma unroll
    for (int m = 0; m < 2; ++m) {
#pragma unroll
      for (int j = 0; j < 4; ++j) {
        float p0 = __expf(s_acc[m][0][j]);
        float p1 = __expf(s_acc[m][1][j]);
        float p2 = __expf(s_acc[m][2][j]);
        float p3 = __expf(s_acc[m][3][j]);
        l_part[m][j] += (p0 + p1) + (p2 + p3);
        int row = m * 16 + l4 * 4 + j;
        int swr = (row & 7) << 4;
        char* pr = (char*)pw + row * 128;
        *(unsigned short*)(pr + ((l15 * 2) ^ swr))      = f2bf(p0);
        *(unsigned short*)(pr + ((32 + l15 * 2) ^ swr)) = f2bf(p1);
        *(unsigned short*)(pr + ((64 + l15 * 2) ^ swr)) = f2bf(p2);
        *(unsigned short*)(pr + ((96 + l15 * 2) ^ swr)) = f2bf(p3);
      }
    }
#pragma unroll
    for (int ks = 0; ks < 2; ++ks) {
      short8 pf[2];
#pragma unroll
      for (int m = 0; m < 2; ++m)
        pf[m] = *(const short8*)((const char*)pw + (m * 16 + l15) * 128 +
                                 ((ks * 64 + l4 * 16) ^ swl));
#pragma unroll
      for (int c = 0; c < 4; ++c) {
        short8 vf = *(const short8*)((const char*)Vs + (c * 16 + l15) * 128 +
                                     ((ks * 64 + l4 * 16) ^ swl));
#pragma unroll
        for (int m = 0; m < 2; ++m)
          o_acc[m][c] = mfma16(pf[m], vf, o_acc[m][c]);
      }
    }
  }
#pragma unroll
  for (int m = 0; m < 2; ++m) {
#pragma unroll
    for (int j = 0; j < 4; ++j) {
      float l = l_part[m][j];
      l += __shfl_xor(l, 1, 64);
      l += __shfl_xor(l, 2, 64);
      l += __shfl_xor(l, 4, 64);
      l += __shfl_xor(l, 8, 64);
      float inv = 1.0f / l;
      int row = b * 2048 + q0 + w * 32 + m * 16 + l4 * 4 + j;
#pragma unroll
      for (int c = 0; c < 4; ++c) {
        int col = h * 64 + c * 16 + l15;
        O[(size_t)row * 1024 + col] = f2bf(o_acc[m][c][j] * inv);
      }
    }
  }
}

// ----------------------- residual add + LayerNorm --------------------------
__global__ void add_ln(const float* __restrict__ res,
                       const unsigned short* __restrict__ delta,
                       const float* __restrict__ g,
                       const float* __restrict__ beta,
                       float* __restrict__ out_f32,
                       unsigned short* __restrict__ out_bf) {
  __shared__ float red1[4], red2[4];
  const int row = blockIdx.x;
  const int t = threadIdx.x;
  const int lane = t & 63, w = t >> 6;
  const size_t base = (size_t)row * 1024 + t * 4;
  float4 rv = *(const float4*)(res + base);
  ushort4 dv = *(const ushort4*)(delta + base);
  float v0 = rv.x + bf2f(dv.x);
  float v1 = rv.y + bf2f(dv.y);
  float v2 = rv.z + bf2f(dv.z);
  float v3 = rv.w + bf2f(dv.w);
  float s = v0 + v1 + v2 + v3;
#pragma unroll
  for (int m = 1; m <= 32; m <<= 1) s += __shfl_xor(s, m, 64);
  if (lane == 0) red1[w] = s;
  __syncthreads();
  float mean = (red1[0] + red1[1] + red1[2] + red1[3]) * (1.0f / 1024.0f);
  float d0 = v0 - mean, d1 = v1 - mean, d2 = v2 - mean, d3 = v3 - mean;
  float q = d0 * d0 + d1 * d1 + d2 * d2 + d3 * d3;
#pragma unroll
  for (int m = 1; m <= 32; m <<= 1) q += __shfl_xor(q, m, 64);
  if (lane == 0) red2[w] = q;
  __syncthreads();
  float var = (red2[0] + red2[1] + red2[2] + red2[3]) * (1.0f / 1024.0f);
  float rstd = rsqrtf(var + 1e-5f);
  float4 gv = *(const float4*)(g + t * 4);
  float4 bv = *(const float4*)(beta + t * 4);
  float y0 = d0 * rstd * gv.x + bv.x;
  float y1 = d1 * rstd * gv.y + bv.y;
  float y2 = d2 * rstd * gv.z + bv.z;
  float y3 = d3 * rstd * gv.w + bv.w;
  float4 ov = {y0, y1, y2, y3};
  *(float4*)(out_f32 + base) = ov;
  if (out_bf) {
    ushort4 obv;
    obv.x = f2bf(y0); obv.y = f2bf(y1); obv.z = f2bf(y2); obv.w = f2bf(y3);
    *(ushort4*)(out_bf + base) = obv;
  }
}

// ------------------------------- host --------------------------------------
extern "C" void kernel_launch(void* const* d_in, const int* in_sizes, int n_in,
                              void* d_out, int out_size, void* d_ws, size_t ws_size,
                              hipStream_t stream) {
  const float* x   = (const float*)d_in[0];
  const float* wq  = (const float*)d_in[1];
  const float* bq  = (const float*)d_in[2];
  const float* wk  = (const float*)d_in[3];
  const float* bk  = (const float*)d_in[4];
  const float* wv  = (const float*)d_in[5];
  const float* bv  = (const float*)d_in[6];
  const float* wo  = (const float*)d_in[7];
  const float* bo  = (const float*)d_in[8];
  const float* w1  = (const float*)d_in[9];
  const float* b1  = (const float*)d_in[10];
  const float* w2  = (const float*)d_in[11];
  const float* b2  = (const float*)d_in[12];
  const float* g1  = (const float*)d_in[13];
  const float* be1 = (const float*)d_in[14];
  const float* g2  = (const float*)d_in[15];
  const float* be2 = (const float*)d_in[16];
  float* out = (float*)d_out;

  char* wsb = (char*)d_ws;
  const size_t MB = 1ull << 20;
  unsigned short* x_bf  = (unsigned short*)(wsb + 0 * MB);
  unsigned short* qb    = (unsigned short*)(wsb + 16 * MB);
  unsigned short* kb    = (unsigned short*)(wsb + 32 * MB);
  unsigned short* vb    = (unsigned short*)(wsb + 48 * MB);
  unsigned short* vt    = (unsigned short*)(wsb + 64 * MB);
  unsigned short* ob    = (unsigned short*)(wsb + 80 * MB);
  unsigned short* hb    = (unsigned short*)(wsb + 0 * MB);   // reuse
  unsigned short* ff_bf = (unsigned short*)(wsb + 64 * MB);  // reuse
  unsigned short* wq_bf = (unsigned short*)(wsb + 96 * MB);
  unsigned short* wk_bf = (unsigned short*)(wsb + 98 * MB);
  unsigned short* wv_bf = (unsigned short*)(wsb + 100 * MB);
  unsigned short* wo_bf = (unsigned short*)(wsb + 102 * MB);
  unsigned short* w1_bf = (unsigned short*)(wsb + 104 * MB);
  unsigned short* w2_bf = (unsigned short*)(wsb + 112 * MB);
  unsigned short* ao_bf = (unsigned short*)(wsb + 120 * MB);
  float*          x1    = (float*)(wsb + 136 * MB);
  unsigned short* x1_bf = (unsigned short*)(wsb + 168 * MB);

  auto cast = [&](const float* in, unsigned short* o, int n) {
    int n4 = n / 4;
    int blocks = (n4 + 255) / 256;
    if (blocks > 2048) blocks = 2048;
    cast_f32_bf16<<<blocks, 256, 0, stream>>>(in, o, n4);
  };
  cast(x, x_bf, 4 * 2048 * 1024);
  cast(wq, wq_bf, 1024 * 1024);
  cast(wk, wk_bf, 1024 * 1024);
  cast(wv, wv_bf, 1024 * 1024);
  cast(wo, wo_bf, 1024 * 1024);
  cast(w1, w1_bf, 4096 * 1024);
  cast(w2, w2_bf, 1024 * 4096);

  dim3 blk(256);
  gemm_bt<2><<<dim3(8, 64), blk, 0, stream>>>(x_bf, wq_bf, bq, qb, 8192, 1024, 1024);
  gemm_bt<0><<<dim3(8, 64), blk, 0, stream>>>(x_bf, wk_bf, bk, kb, 8192, 1024, 1024);
  gemm_bt<0><<<dim3(8, 64), blk, 0, stream>>>(x_bf, wv_bf, bv, vb, 8192, 1024, 1024);
  transpose_v<<<dim3(32, 64), blk, 0, stream>>>(vb, vt);
  attn_fwd<<<dim3(16, 64), blk, 0, stream>>>(qb, kb, vt, ob);
  gemm_bt<0><<<dim3(8, 64), blk, 0, stream>>>(ob, wo_bf, bo, ao_bf, 8192, 1024, 1024);
  add_ln<<<8192, blk, 0, stream>>>(x, ao_bf, g1, be1, x1, x1_bf);
  // FF1: 256^2 8-phase pipelined GEMM, GELU fused. grid 32x16=512 (%8==0).
  gemm_bt8<1><<<512, 512, 0, stream>>>(x1_bf, w1_bf, b1, hb, 8192, 4096, 1024, 16);
  gemm_bt<0><<<dim3(8, 64), blk, 0, stream>>>(hb, w2_bf, b2, ff_bf, 8192, 1024, 4096);
  add_ln<<<8192, blk, 0, stream>>>(x1, ff_bf, g2, be2, out, (unsigned short*)nullptr);
}